// Round 4
// baseline (2730.768 us; speedup 1.0000x reference)
//
#include <hip/hip_runtime.h>
#include <cstdint>

#define DIM 128

typedef unsigned short bf16t;

__device__ __forceinline__ unsigned short f2bf_bits(float f) {
    union { float f; uint32_t u; } x; x.f = f;
    uint32_t r = x.u + 0x7FFFu + ((x.u >> 16) & 1u);  // RN-even
    return (unsigned short)(r >> 16);
}

template <typename T> struct VecIO;
template <> struct VecIO<float> {
    static __device__ __forceinline__ float2 ld2(const float* p, size_t i) {
        return ((const float2*)p)[i];
    }
    static __device__ __forceinline__ void st2(float* p, size_t i, float2 v) {
        ((float2*)p)[i] = v;
    }
    static __device__ __forceinline__ void st4(float* p, float4 v) {
        *(float4*)p = v;
    }
};
template <> struct VecIO<bf16t> {
    static __device__ __forceinline__ float2 ld2(const bf16t* p, size_t i) {
        uint32_t u = ((const uint32_t*)p)[i];
        union { uint32_t u; float f; } a, b;
        a.u = u << 16; b.u = u & 0xFFFF0000u;
        return make_float2(a.f, b.f);
    }
    static __device__ __forceinline__ void st2(bf16t* p, size_t i, float2 v) {
        uint32_t lo = f2bf_bits(v.x), hi = f2bf_bits(v.y);
        ((uint32_t*)p)[i] = lo | (hi << 16);
    }
    static __device__ __forceinline__ void st4(bf16t* p, float4 v) {
        uint32_t lo = (uint32_t)f2bf_bits(v.x) | ((uint32_t)f2bf_bits(v.y) << 16);
        uint32_t hi = (uint32_t)f2bf_bits(v.z) | ((uint32_t)f2bf_bits(v.w) << 16);
        *(uint2*)p = make_uint2(lo, hi);
    }
};

__device__ __forceinline__ float wave_reduce_sum(float v) {
    #pragma unroll
    for (int m = 32; m > 0; m >>= 1) v += __shfl_xor(v, m, 64);
    return v;
}

// ---------------- fused CSR build (5 matrices via blockIdx.y) ----------------
struct P5ci { const int* p[5]; };
struct P5cf { const float* p[5]; };
struct P5i  { int* p[5]; };
struct P5f  { float* p[5]; };
struct I5   { int v[5]; };

__global__ __launch_bounds__(256) void k_hist_all(P5ci rows, I5 E, P5i counts) {
    int y = blockIdx.y;
    int e = blockIdx.x * 256 + threadIdx.x;
    if (e < E.v[y]) atomicAdd(&counts.p[y][rows.p[y][e] + 1], 1);
}

// in-place inclusive scan of d[y][0..n) in 1024-elem tiles; bsums[y][b] = tile total
__global__ __launch_bounds__(256) void k_scan_tile_m(P5i dd, I5 nn, P5i bsums, int has_bsums) {
    __shared__ int sh[256];
    int y = blockIdx.y;
    int* d = dd.p[y];
    int n = nn.v[y];
    int t = threadIdx.x;
    int base = blockIdx.x * 1024 + t * 4;
    int v0 = (base + 0 < n) ? d[base + 0] : 0;
    int v1 = (base + 1 < n) ? d[base + 1] : 0;
    int v2 = (base + 2 < n) ? d[base + 2] : 0;
    int v3 = (base + 3 < n) ? d[base + 3] : 0;
    v1 += v0; v2 += v1; v3 += v2;
    sh[t] = v3;
    __syncthreads();
    #pragma unroll
    for (int off = 1; off < 256; off <<= 1) {
        int x = (t >= off) ? sh[t - off] : 0;
        __syncthreads();
        if (t >= off) sh[t] += x;
        __syncthreads();
    }
    int excl = (t > 0) ? sh[t - 1] : 0;
    v0 += excl; v1 += excl; v2 += excl; v3 += excl;
    if (base + 0 < n) d[base + 0] = v0;
    if (base + 1 < n) d[base + 1] = v1;
    if (base + 2 < n) d[base + 2] = v2;
    if (base + 3 < n) d[base + 3] = v3;
    if (t == 255 && has_bsums) bsums.p[y][blockIdx.x] = sh[255];
}

__global__ __launch_bounds__(256) void k_scan_add_m(P5i dd, I5 nn, P5ci bsums) {
    if (blockIdx.x == 0) return;
    int y = blockIdx.y;
    int* d = dd.p[y];
    int n = nn.v[y];
    int add = bsums.p[y][blockIdx.x - 1];
    int base = blockIdx.x * 1024 + threadIdx.x * 4;
    #pragma unroll
    for (int i = 0; i < 4; ++i)
        if (base + i < n) d[base + i] += add;
}

__global__ __launch_bounds__(256) void k_scatter_all(P5ci rows, P5ci cols, P5cf vals,
                                                     I5 E, P5i cursor,
                                                     P5i scol, P5f sval) {
    int y = blockIdx.y;
    int e = blockIdx.x * 256 + threadIdx.x;
    if (e < E.v[y]) {
        int r = rows.p[y][e];
        int p = atomicAdd(&cursor.p[y][r], 1);
        scol.p[y][p] = cols.p[y][e];
        sval.p[y][p] = vals.p[y][e];
    }
}

// ---------------- small prep ----------------
// w[k] = sum_d attn_mat[k][d] * attn[d]
__global__ __launch_bounds__(128) void k_attn_w(const float* __restrict__ attn_mat,
                                                const float* __restrict__ attn,
                                                float* __restrict__ w) {
    int k = threadIdx.x;
    float s = 0.f;
    for (int d = 0; d < DIM; ++d) s += attn_mat[k * DIM + d] * attn[d];
    w[k] = s;
}

// wtg[g][d][k] = gw[g][k][d]
__global__ __launch_bounds__(128) void k_twt(const float* __restrict__ gw,
                                             float* __restrict__ wtg) {
    int g = blockIdx.y, d = blockIdx.x, k = threadIdx.x;
    wtg[((size_t)g * DIM + d) * DIM + k] = gw[((size_t)g * DIM + k) * DIM + d];
}

template <typename T>
__global__ __launch_bounds__(256) void k_cvt(const float* __restrict__ src,
                                             T* __restrict__ dst, int n2) {
    int i = blockIdx.x * 256 + threadIdx.x;
    if (i < n2) VecIO<T>::st2(dst, i, ((const float2*)src)[i]);
}

// ---------------- channel attention + mix (+0.5*add) ----------------
template <typename TI>
__global__ __launch_bounds__(256) void k_attn_mix(const TI* __restrict__ e1,
                                                  const TI* __restrict__ e2,
                                                  const TI* __restrict__ e3,
                                                  const TI* __restrict__ add,
                                                  const float* __restrict__ w,
                                                  float* __restrict__ out, int n) {
    int wid = threadIdx.x >> 6, lane = threadIdx.x & 63;
    int u = blockIdx.x * 4 + wid;
    if (u >= n) return;
    size_t idx = (size_t)u * 64 + lane;
    float2 a = VecIO<TI>::ld2(e1, idx);
    float2 b = VecIO<TI>::ld2(e2, idx);
    float2 c = VecIO<TI>::ld2(e3, idx);
    float2 s = VecIO<TI>::ld2(add, idx);
    float2 wv = ((const float2*)w)[lane];
    float t1 = a.x * wv.x + a.y * wv.y;
    float t2 = b.x * wv.x + b.y * wv.y;
    float t3 = c.x * wv.x + c.y * wv.y;
    #pragma unroll
    for (int m = 32; m > 0; m >>= 1) {
        t1 += __shfl_xor(t1, m, 64);
        t2 += __shfl_xor(t2, m, 64);
        t3 += __shfl_xor(t3, m, 64);
    }
    float mx = fmaxf(t1, fmaxf(t2, t3));
    float x1 = __expf(t1 - mx), x2 = __expf(t2 - mx), x3 = __expf(t3 - mx);
    float inv = 1.f / (x1 + x2 + x3);
    x1 *= inv; x2 *= inv; x3 *= inv;
    float2 o;
    o.x = x1 * a.x + x2 * b.x + x3 * c.x + 0.5f * s.x;
    o.y = x1 * a.y + x2 * b.y + x3 * c.y + 0.5f * s.y;
    ((float2*)out)[idx] = o;
}

// ---------------- CSR spmm + fused l2-normalize accumulate ----------------
// y[r] = sum_j val_j * x[col_j];  acc[r] += y[r] / max(||y[r]||, 1e-12)
template <typename TI, typename TO, typename TA>
__global__ __launch_bounds__(256) void k_spmm(const int* __restrict__ off,
                                              const int* __restrict__ scol,
                                              const float* __restrict__ sval,
                                              const TI* __restrict__ x,
                                              TO* __restrict__ y,
                                              TA* __restrict__ acc, int n) {
    int wid = threadIdx.x >> 6, lane = threadIdx.x & 63;
    int r = blockIdx.x * 4 + wid;
    if (r >= n) return;
    int b = off[r], e = off[r + 1];
    float2 s = make_float2(0.f, 0.f);
    for (int j = b; j < e; ++j) {
        int c = scol[j];
        float v = sval[j];
        float2 xv = VecIO<TI>::ld2(x, (size_t)c * 64 + lane);
        s.x = fmaf(v, xv.x, s.x);
        s.y = fmaf(v, xv.y, s.y);
    }
    size_t idx = (size_t)r * 64 + lane;
    VecIO<TO>::st2(y, idx, s);
    float q = wave_reduce_sum(s.x * s.x + s.y * s.y);
    float rn = 1.f / fmaxf(sqrtf(q), 1e-12f);
    float2 av = VecIO<TA>::ld2(acc, idx);
    av.x = fmaf(s.x, rn, av.x);
    av.y = fmaf(s.y, rn, av.y);
    VecIO<TA>::st2(acc, idx, av);
}

// ---------------- gated GEMM: out = ue * sigmoid(ue @ W_g + b_g) ----------------
// 32 rows/block, 4x4 register blocking. thread: cg=tid&31 -> cols 4cg..4cg+3,
// rg=tid>>5 -> rows 4rg..4rg+3. A tile in LDS (16KB); W^T cols stream from L1/L2.
template <typename T>
__global__ __launch_bounds__(256, 4) void k_gate(const float* __restrict__ ue,
                                                 const float* __restrict__ wtg,
                                                 const float* __restrict__ gb,
                                                 T* __restrict__ cbase,
                                                 T* __restrict__ abase, int U) {
    __shared__ float us[32][DIM];
    int g = blockIdx.y;
    const float* wt = wtg + (size_t)g * DIM * DIM;
    int tid = threadIdx.x;
    int cg = tid & 31, rg = tid >> 5;
    int row0 = blockIdx.x * 32;
    int nr = U - row0; if (nr > 32) nr = 32;
    {
        const float4* src = (const float4*)(ue + (size_t)row0 * DIM);
        float4* dst = (float4*)us;
        int tot = nr * 32;
        for (int i = tid; i < tot; i += 256) dst[i] = src[i];
    }
    __syncthreads();
    float acc[4][4];
    #pragma unroll
    for (int i = 0; i < 4; ++i)
        #pragma unroll
        for (int j = 0; j < 4; ++j) acc[i][j] = 0.f;
    const float4* wr0 = (const float4*)(wt + (size_t)(4 * cg + 0) * DIM);
    const float4* wr1 = (const float4*)(wt + (size_t)(4 * cg + 1) * DIM);
    const float4* wr2 = (const float4*)(wt + (size_t)(4 * cg + 2) * DIM);
    const float4* wr3 = (const float4*)(wt + (size_t)(4 * cg + 3) * DIM);
    #pragma unroll 4
    for (int kc = 0; kc < 32; ++kc) {
        float4 w0 = wr0[kc], w1 = wr1[kc], w2 = wr2[kc], w3 = wr3[kc];
        float4 a0 = *(const float4*)&us[4 * rg + 0][kc * 4];
        float4 a1 = *(const float4*)&us[4 * rg + 1][kc * 4];
        float4 a2 = *(const float4*)&us[4 * rg + 2][kc * 4];
        float4 a3 = *(const float4*)&us[4 * rg + 3][kc * 4];
        #define GDOT(i, ar) \
            acc[i][0] = fmaf(ar.x, w0.x, fmaf(ar.y, w0.y, fmaf(ar.z, w0.z, fmaf(ar.w, w0.w, acc[i][0])))); \
            acc[i][1] = fmaf(ar.x, w1.x, fmaf(ar.y, w1.y, fmaf(ar.z, w1.z, fmaf(ar.w, w1.w, acc[i][1])))); \
            acc[i][2] = fmaf(ar.x, w2.x, fmaf(ar.y, w2.y, fmaf(ar.z, w2.z, fmaf(ar.w, w2.w, acc[i][2])))); \
            acc[i][3] = fmaf(ar.x, w3.x, fmaf(ar.y, w3.y, fmaf(ar.z, w3.z, fmaf(ar.w, w3.w, acc[i][3]))))
        GDOT(0, a0); GDOT(1, a1); GDOT(2, a2); GDOT(3, a3);
        #undef GDOT
    }
    float bv0 = gb[g * DIM + 4 * cg + 0];
    float bv1 = gb[g * DIM + 4 * cg + 1];
    float bv2 = gb[g * DIM + 4 * cg + 2];
    float bv3 = gb[g * DIM + 4 * cg + 3];
    size_t UD = (size_t)U * DIM;
    T* cOut = cbase + (size_t)g * UD;
    T* aOut = abase + (size_t)g * UD;
    #pragma unroll
    for (int i = 0; i < 4; ++i) {
        int lr = 4 * rg + i;
        int r = row0 + lr;
        if (r < U) {
            float4 o;
            o.x = us[lr][4 * cg + 0] / (1.f + __expf(-(acc[i][0] + bv0)));
            o.y = us[lr][4 * cg + 1] / (1.f + __expf(-(acc[i][1] + bv1)));
            o.z = us[lr][4 * cg + 2] / (1.f + __expf(-(acc[i][2] + bv2)));
            o.w = us[lr][4 * cg + 3] / (1.f + __expf(-(acc[i][3] + bv3)));
            size_t oo = (size_t)r * DIM + 4 * cg;
            VecIO<T>::st4(cOut + oo, o);
            VecIO<T>::st4(aOut + oo, o);
        }
    }
}

// ---------------- orchestration ----------------
template <typename T>
static void run_all(const float* user_emb, const float* item_emb,
                    const float* gating_w, const float* gating_b,
                    const float* attn, const float* attn_mat,
                    const int* hs_row, const int* hs_col, const float* hs_val, int E_hs,
                    const int* hj_row, const int* hj_col, const float* hj_val, int E_hj,
                    const int* hp_row, const int* hp_col, const float* hp_val, int E_hp,
                    const int* r_row, const int* r_col, const float* r_val, int E_r,
                    int U, int I, float* out_user, float* out_item,
                    char* ws, hipStream_t stream) {
    const size_t UD = (size_t)U * DIM, ID = (size_t)I * DIM;
    char* p = ws;
    auto alloc = [&](size_t bytes) -> void* {
        void* r = (void*)p;
        p += (bytes + 255) & ~(size_t)255;
        return r;
    };
    T* S[5];
    for (int i = 0; i < 5; ++i) S[i] = (T*)alloc(UD * sizeof(T));  // contiguous: gate writes S[0..3]
    T* A = (T*)alloc(4 * UD * sizeof(T));                          // A1,A2,A3,AS contiguous
    T* itemA = (T*)alloc(ID * sizeof(T));
    T* itemB = (T*)alloc(ID * sizeof(T));
    float* wv  = (float*)alloc(DIM * sizeof(float));
    float* wtg = (float*)alloc(4 * DIM * DIM * sizeof(float));
    // contiguous offset + cursor regions: [hs|hj|hp|ru : U+1 each][ri : I+1]
    size_t offT = 4 * (size_t)(U + 1) + (size_t)(I + 1);
    int* off_all    = (int*)alloc(offT * 4);
    int* cursor_all = (int*)alloc(offT * 4);
    int* bsums_all  = (int*)alloc(5 * 1024 * 4);
    int*   scol_hs = (int*)alloc((size_t)E_hs * 4);
    float* sval_hs = (float*)alloc((size_t)E_hs * 4);
    int*   scol_hj = (int*)alloc((size_t)E_hj * 4);
    float* sval_hj = (float*)alloc((size_t)E_hj * 4);
    int*   scol_hp = (int*)alloc((size_t)E_hp * 4);
    float* sval_hp = (float*)alloc((size_t)E_hp * 4);
    int*   scol_ru = (int*)alloc((size_t)E_r * 4);
    float* sval_ru = (float*)alloc((size_t)E_r * 4);
    int*   scol_ri = (int*)alloc((size_t)E_r * 4);
    float* sval_ri = (float*)alloc((size_t)E_r * 4);

    int* off_hs = off_all;
    int* off_hj = off_all + (U + 1);
    int* off_hp = off_all + 2 * (size_t)(U + 1);
    int* off_ru = off_all + 3 * (size_t)(U + 1);
    int* off_ri = off_all + 4 * (size_t)(U + 1);

    // ---- fused CSR build for all 5 operators ----
    {
        P5ci rows{{hs_row, hj_row, hp_row, r_row, r_col}};
        P5ci cols{{hs_col, hj_col, hp_col, r_col, r_row}};
        P5cf vals{{hs_val, hj_val, hp_val, r_val, r_val}};
        I5 Es{{E_hs, E_hj, E_hp, E_r, E_r}};
        P5i counts{{off_hs, off_hj, off_hp, off_ru, off_ri}};
        P5i curs{{cursor_all, cursor_all + (U + 1), cursor_all + 2 * (size_t)(U + 1),
                  cursor_all + 3 * (size_t)(U + 1), cursor_all + 4 * (size_t)(U + 1)}};
        P5i scols{{scol_hs, scol_hj, scol_hp, scol_ru, scol_ri}};
        P5f svals{{sval_hs, sval_hj, sval_hp, sval_ru, sval_ri}};
        I5 ns{{U + 1, U + 1, U + 1, U + 1, I + 1}};
        int nbU = (U + 1 + 1023) / 1024, nbI = (I + 1 + 1023) / 1024;
        I5 nbs{{nbU, nbU, nbU, nbU, nbI}};
        int nbMax = nbU > nbI ? nbU : nbI;
        P5i bs{{bsums_all, bsums_all + 1024, bsums_all + 2048, bsums_all + 3072, bsums_all + 4096}};
        P5ci bsc{{bsums_all, bsums_all + 1024, bsums_all + 2048, bsums_all + 3072, bsums_all + 4096}};
        int maxE = E_hs;
        if (E_hj > maxE) maxE = E_hj;
        if (E_hp > maxE) maxE = E_hp;
        if (E_r  > maxE) maxE = E_r;
        int ge = (maxE + 255) / 256;
        P5i nulls{{nullptr, nullptr, nullptr, nullptr, nullptr}};

        hipMemsetAsync(off_all, 0, offT * 4, stream);
        k_hist_all<<<dim3(ge, 5), 256, 0, stream>>>(rows, Es, counts);
        k_scan_tile_m<<<dim3(nbMax, 5), 256, 0, stream>>>(counts, ns, bs, 1);
        k_scan_tile_m<<<dim3(1, 5), 256, 0, stream>>>(bs, nbs, nulls, 0);
        k_scan_add_m<<<dim3(nbMax, 5), 256, 0, stream>>>(counts, ns, bsc);
        hipMemcpyAsync(cursor_all, off_all, offT * 4, hipMemcpyDeviceToDevice, stream);
        k_scatter_all<<<dim3(ge, 5), 256, 0, stream>>>(rows, cols, vals, Es, curs, scols, svals);
    }

    k_attn_w<<<1, 128, 0, stream>>>(attn_mat, attn, wv);
    dim3 tg(DIM, 4);
    k_twt<<<tg, 128, 0, stream>>>(gating_w, wtg);
    dim3 gg((U + 31) / 32, 4);
    k_gate<T><<<gg, 256, 0, stream>>>(user_emb, wtg, gating_b, S[0], A, U);
    k_cvt<T><<<(int)((ID / 2 + 255) / 256), 256, 0, stream>>>(item_emb, itemA, (int)(ID / 2));
    hipMemcpyAsync(out_item, item_emb, ID * sizeof(float), hipMemcpyDeviceToDevice, stream);

    T *A1 = A, *A2 = A + UD, *A3 = A + 2 * UD, *AS = A + 3 * UD;
    T *c1 = S[0], *c2 = S[1], *c3 = S[2], *sp = S[3], *spare = S[4];
    T *itc = itemA, *itn = itemB;
    float* mixed = out_user;  // f32 scratch aliasing output region (fully rewritten later)
    int gbU = (U + 3) / 4, gbI = (I + 3) / 4;

    for (int layer = 0; layer < 2; ++layer) {
        k_attn_mix<T><<<gbU, 256, 0, stream>>>(c1, c2, c3, sp, wv, mixed, U);
        k_spmm<T, T, T><<<gbU, 256, 0, stream>>>(off_hs, scol_hs, sval_hs, c1, spare, A1, U);
        k_spmm<T, T, T><<<gbU, 256, 0, stream>>>(off_hj, scol_hj, sval_hj, c2, c1, A2, U);
        k_spmm<T, T, T><<<gbU, 256, 0, stream>>>(off_hp, scol_hp, sval_hp, c3, c2, A3, U);
        k_spmm<float, T, float><<<gbI, 256, 0, stream>>>(off_ri, scol_ri, sval_ri, mixed, itn, out_item, I);
        k_spmm<T, T, T><<<gbU, 256, 0, stream>>>(off_ru, scol_ru, sval_ru, itc, c3, AS, U);
        // rotate: (c1,c2,c3,sp,spare) <- (spare, c1, c2, c3, sp)  [buffers, not values]
        T* t0 = spare; T* t1 = c1; T* t2 = c2; T* t3 = c3; T* t4 = sp;
        c1 = t0; c2 = t1; c3 = t2; sp = t3; spare = t4;
        T* tt = itc; itc = itn; itn = tt;
    }
    k_attn_mix<T><<<gbU, 256, 0, stream>>>(A1, A2, A3, AS, wv, out_user, U);
}

extern "C" void kernel_launch(void* const* d_in, const int* in_sizes, int n_in,
                              void* d_out, int out_size, void* d_ws, size_t ws_size,
                              hipStream_t stream) {
    const float* user_emb = (const float*)d_in[0];
    const float* item_emb = (const float*)d_in[1];
    const float* gating_w = (const float*)d_in[2];
    const float* gating_b = (const float*)d_in[3];
    const float* attn     = (const float*)d_in[4];
    const float* attn_mat = (const float*)d_in[5];
    const int*   hs_row = (const int*)d_in[6];
    const int*   hs_col = (const int*)d_in[7];
    const float* hs_val = (const float*)d_in[8];
    const int*   hj_row = (const int*)d_in[9];
    const int*   hj_col = (const int*)d_in[10];
    const float* hj_val = (const float*)d_in[11];
    const int*   hp_row = (const int*)d_in[12];
    const int*   hp_col = (const int*)d_in[13];
    const float* hp_val = (const float*)d_in[14];
    const int*   r_row  = (const int*)d_in[15];
    const int*   r_col  = (const int*)d_in[16];
    const float* r_val  = (const float*)d_in[17];

    const int U = in_sizes[0] / DIM;
    const int I = in_sizes[1] / DIM;
    const int E_hs = in_sizes[6], E_hj = in_sizes[9], E_hp = in_sizes[12], E_r = in_sizes[15];
    const size_t UD = (size_t)U * DIM, ID = (size_t)I * DIM;

    float* out_user = (float*)d_out;
    float* out_item = out_user + UD;

    // footprint (256B-aligned per alloc; generous slack)
    size_t csr = 2 * ((size_t)E_hs + E_hj + E_hp + 2 * (size_t)E_r) * 4;
    size_t offs = 2 * (4 * (size_t)(U + 1) + (I + 1)) * 4 + 4 * 5 * 1024 + DIM * 4 +
                  4 * DIM * DIM * 4 + (1 << 16);
    size_t reqF = 9 * UD * 4 + 2 * ID * 4 + csr + offs;

    if (ws_size >= reqF) {
        run_all<float>(user_emb, item_emb, gating_w, gating_b, attn, attn_mat,
                       hs_row, hs_col, hs_val, E_hs, hj_row, hj_col, hj_val, E_hj,
                       hp_row, hp_col, hp_val, E_hp, r_row, r_col, r_val, E_r,
                       U, I, out_user, out_item, (char*)d_ws, stream);
    } else {
        run_all<bf16t>(user_emb, item_emb, gating_w, gating_b, attn, attn_mat,
                       hs_row, hs_col, hs_val, E_hs, hj_row, hj_col, hj_val, E_hj,
                       hp_row, hp_col, hp_val, E_hp, r_row, r_col, r_val, E_r,
                       U, I, out_user, out_item, (char*)d_ws, stream);
    }
}

// Round 7
// 1708.246 us; speedup vs baseline: 1.5986x; 1.5986x over previous
//
#include <hip/hip_runtime.h>
#include <cstdint>

#define DIM 128

typedef unsigned short bf16t;

__device__ __forceinline__ unsigned short f2bf_bits(float f) {
    union { float f; uint32_t u; } x; x.f = f;
    uint32_t r = x.u + 0x7FFFu + ((x.u >> 16) & 1u);  // RN-even
    return (unsigned short)(r >> 16);
}

template <typename T> struct VecIO;
template <> struct VecIO<float> {
    static __device__ __forceinline__ float2 ld2(const float* p, size_t i) {
        return ((const float2*)p)[i];
    }
    static __device__ __forceinline__ void st2(float* p, size_t i, float2 v) {
        ((float2*)p)[i] = v;
    }
    static __device__ __forceinline__ void st4(float* p, float4 v) {
        *(float4*)p = v;
    }
};
template <> struct VecIO<bf16t> {
    static __device__ __forceinline__ float2 ld2(const bf16t* p, size_t i) {
        uint32_t u = ((const uint32_t*)p)[i];
        union { uint32_t u; float f; } a, b;
        a.u = u << 16; b.u = u & 0xFFFF0000u;
        return make_float2(a.f, b.f);
    }
    static __device__ __forceinline__ void st2(bf16t* p, size_t i, float2 v) {
        uint32_t lo = f2bf_bits(v.x), hi = f2bf_bits(v.y);
        ((uint32_t*)p)[i] = lo | (hi << 16);
    }
    static __device__ __forceinline__ void st4(bf16t* p, float4 v) {
        uint32_t lo = (uint32_t)f2bf_bits(v.x) | ((uint32_t)f2bf_bits(v.y) << 16);
        uint32_t hi = (uint32_t)f2bf_bits(v.z) | ((uint32_t)f2bf_bits(v.w) << 16);
        *(uint2*)p = make_uint2(lo, hi);
    }
};

__device__ __forceinline__ float wave_reduce_sum(float v) {
    #pragma unroll
    for (int m = 32; m > 0; m >>= 1) v += __shfl_xor(v, m, 64);
    return v;
}

// ---------------- fused CSR build (5 matrices via blockIdx.y) ----------------
struct P5ci { const int* p[5]; };
struct P5cf { const float* p[5]; };
struct P5i  { int* p[5]; };
struct P5f  { float* p[5]; };
struct I5   { int v[5]; };

__global__ __launch_bounds__(256) void k_hist_all(P5ci rows, I5 E, P5i counts) {
    int y = blockIdx.y;
    int e = blockIdx.x * 256 + threadIdx.x;
    if (e < E.v[y]) atomicAdd(&counts.p[y][rows.p[y][e] + 1], 1);
}

// in-place inclusive scan of d[y][0..n) in 1024-elem tiles; bsums[y][b] = tile total
__global__ __launch_bounds__(256) void k_scan_tile_m(P5i dd, I5 nn, P5i bsums, int has_bsums) {
    __shared__ int sh[256];
    int y = blockIdx.y;
    int* d = dd.p[y];
    int n = nn.v[y];
    int t = threadIdx.x;
    int base = blockIdx.x * 1024 + t * 4;
    int v0 = (base + 0 < n) ? d[base + 0] : 0;
    int v1 = (base + 1 < n) ? d[base + 1] : 0;
    int v2 = (base + 2 < n) ? d[base + 2] : 0;
    int v3 = (base + 3 < n) ? d[base + 3] : 0;
    v1 += v0; v2 += v1; v3 += v2;
    sh[t] = v3;
    __syncthreads();
    #pragma unroll
    for (int off = 1; off < 256; off <<= 1) {
        int x = (t >= off) ? sh[t - off] : 0;
        __syncthreads();
        if (t >= off) sh[t] += x;
        __syncthreads();
    }
    int excl = (t > 0) ? sh[t - 1] : 0;
    v0 += excl; v1 += excl; v2 += excl; v3 += excl;
    if (base + 0 < n) d[base + 0] = v0;
    if (base + 1 < n) d[base + 1] = v1;
    if (base + 2 < n) d[base + 2] = v2;
    if (base + 3 < n) d[base + 3] = v3;
    if (t == 255 && has_bsums) bsums.p[y][blockIdx.x] = sh[255];
}

__global__ __launch_bounds__(256) void k_scan_add_m(P5i dd, I5 nn, P5ci bsums) {
    if (blockIdx.x == 0) return;
    int y = blockIdx.y;
    int* d = dd.p[y];
    int n = nn.v[y];
    int add = bsums.p[y][blockIdx.x - 1];
    int base = blockIdx.x * 1024 + threadIdx.x * 4;
    #pragma unroll
    for (int i = 0; i < 4; ++i)
        if (base + i < n) d[base + i] += add;
}

__global__ __launch_bounds__(256) void k_scatter_all(P5ci rows, P5ci cols, P5cf vals,
                                                     I5 E, P5i cursor,
                                                     P5i scol, P5f sval) {
    int y = blockIdx.y;
    int e = blockIdx.x * 256 + threadIdx.x;
    if (e < E.v[y]) {
        int r = rows.p[y][e];
        int p = atomicAdd(&cursor.p[y][r], 1);
        scol.p[y][p] = cols.p[y][e];
        sval.p[y][p] = vals.p[y][e];
    }
}

// ---------------- small prep ----------------
// w[k] = sum_d attn_mat[k][d] * attn[d]
__global__ __launch_bounds__(128) void k_attn_w(const float* __restrict__ attn_mat,
                                                const float* __restrict__ attn,
                                                float* __restrict__ w) {
    int k = threadIdx.x;
    float s = 0.f;
    for (int d = 0; d < DIM; ++d) s += attn_mat[k * DIM + d] * attn[d];
    w[k] = s;
}

template <typename T>
__global__ __launch_bounds__(256) void k_cvt(const float* __restrict__ src,
                                             T* __restrict__ dst, int n2) {
    int i = blockIdx.x * 256 + threadIdx.x;
    if (i < n2) VecIO<T>::st2(dst, i, ((const float2*)src)[i]);
}

// ---------------- channel attention + mix (+0.5*add) ----------------
template <typename TI>
__global__ __launch_bounds__(256) void k_attn_mix(const TI* __restrict__ e1,
                                                  const TI* __restrict__ e2,
                                                  const TI* __restrict__ e3,
                                                  const TI* __restrict__ add,
                                                  const float* __restrict__ w,
                                                  float* __restrict__ out, int n) {
    int wid = threadIdx.x >> 6, lane = threadIdx.x & 63;
    int u = blockIdx.x * 4 + wid;
    if (u >= n) return;
    size_t idx = (size_t)u * 64 + lane;
    float2 a = VecIO<TI>::ld2(e1, idx);
    float2 b = VecIO<TI>::ld2(e2, idx);
    float2 c = VecIO<TI>::ld2(e3, idx);
    float2 s = VecIO<TI>::ld2(add, idx);
    float2 wv = ((const float2*)w)[lane];
    float t1 = a.x * wv.x + a.y * wv.y;
    float t2 = b.x * wv.x + b.y * wv.y;
    float t3 = c.x * wv.x + c.y * wv.y;
    #pragma unroll
    for (int m = 32; m > 0; m >>= 1) {
        t1 += __shfl_xor(t1, m, 64);
        t2 += __shfl_xor(t2, m, 64);
        t3 += __shfl_xor(t3, m, 64);
    }
    float mx = fmaxf(t1, fmaxf(t2, t3));
    float x1 = __expf(t1 - mx), x2 = __expf(t2 - mx), x3 = __expf(t3 - mx);
    float inv = 1.f / (x1 + x2 + x3);
    x1 *= inv; x2 *= inv; x3 *= inv;
    float2 o;
    o.x = x1 * a.x + x2 * b.x + x3 * c.x + 0.5f * s.x;
    o.y = x1 * a.y + x2 * b.y + x3 * c.y + 0.5f * s.y;
    ((float2*)out)[idx] = o;
}

// ---------------- CSR spmm + fused l2-normalize accumulate ----------------
// y[r] = sum_j val_j * x[col_j];  acc[r] += y[r] / max(||y[r]||, 1e-12)
// 4x edge unroll -> 4 row-gathers in flight per wave.
template <typename TI, typename TO, typename TA>
__global__ __launch_bounds__(256) void k_spmm(const int* __restrict__ off,
                                              const int* __restrict__ scol,
                                              const float* __restrict__ sval,
                                              const TI* __restrict__ x,
                                              TO* __restrict__ y,
                                              TA* __restrict__ acc, int n) {
    int wid = threadIdx.x >> 6, lane = threadIdx.x & 63;
    int r = blockIdx.x * 4 + wid;
    if (r >= n) return;
    int b = off[r], e = off[r + 1];
    float2 s = make_float2(0.f, 0.f);
    int j = b;
    for (; j + 4 <= e; j += 4) {
        int c0 = scol[j + 0], c1 = scol[j + 1], c2 = scol[j + 2], c3 = scol[j + 3];
        float v0 = sval[j + 0], v1 = sval[j + 1], v2 = sval[j + 2], v3 = sval[j + 3];
        float2 x0 = VecIO<TI>::ld2(x, (size_t)c0 * 64 + lane);
        float2 x1 = VecIO<TI>::ld2(x, (size_t)c1 * 64 + lane);
        float2 x2 = VecIO<TI>::ld2(x, (size_t)c2 * 64 + lane);
        float2 x3 = VecIO<TI>::ld2(x, (size_t)c3 * 64 + lane);
        s.x = fmaf(v0, x0.x, s.x); s.y = fmaf(v0, x0.y, s.y);
        s.x = fmaf(v1, x1.x, s.x); s.y = fmaf(v1, x1.y, s.y);
        s.x = fmaf(v2, x2.x, s.x); s.y = fmaf(v2, x2.y, s.y);
        s.x = fmaf(v3, x3.x, s.x); s.y = fmaf(v3, x3.y, s.y);
    }
    for (; j < e; ++j) {
        int c = scol[j];
        float v = sval[j];
        float2 xv = VecIO<TI>::ld2(x, (size_t)c * 64 + lane);
        s.x = fmaf(v, xv.x, s.x);
        s.y = fmaf(v, xv.y, s.y);
    }
    size_t idx = (size_t)r * 64 + lane;
    VecIO<TO>::st2(y, idx, s);
    float q = wave_reduce_sum(s.x * s.x + s.y * s.y);
    float rn = 1.f / fmaxf(sqrtf(q), 1e-12f);
    float2 av = VecIO<TA>::ld2(acc, idx);
    av.x = fmaf(s.x, rn, av.x);
    av.y = fmaf(s.y, rn, av.y);
    VecIO<TA>::st2(acc, idx, av);
}

// ---------------- gated GEMM: out = ue * sigmoid(ue @ W_g + b_g) ----------------
// W is used in its NATIVE [k][c] layout: lane cg reads W[k][4cg..4cg+3] -> fully
// coalesced 512B wave reads (L1/L2-resident, 64KB/gate). 64 rows/block in LDS,
// 8x4 register blocking; A-reads are same-address LDS broadcasts (conflict-free).
template <typename T>
__global__ __launch_bounds__(256, 4) void k_gate(const float* __restrict__ ue,
                                                 const float* __restrict__ gw,
                                                 const float* __restrict__ gb,
                                                 T* __restrict__ cbase,
                                                 T* __restrict__ abase, int U) {
    __shared__ float us[64][DIM];
    int g = blockIdx.y;
    const float4* Wv = (const float4*)(gw + (size_t)g * DIM * DIM);  // [k][c4]
    int tid = threadIdx.x;
    int cg = tid & 31, rg = tid >> 5;  // cols 4cg..4cg+3; local rows 8rg..8rg+7
    int row0 = blockIdx.x * 64;
    int nr = U - row0; if (nr > 64) nr = 64;
    {
        const float4* src = (const float4*)(ue + (size_t)row0 * DIM);
        float4* dst = (float4*)us;
        int tot = nr * 32;
        for (int i = tid; i < tot; i += 256) dst[i] = src[i];
    }
    __syncthreads();
    float acc[8][4];
    #pragma unroll
    for (int i = 0; i < 8; ++i) {
        acc[i][0] = 0.f; acc[i][1] = 0.f; acc[i][2] = 0.f; acc[i][3] = 0.f;
    }
    #pragma unroll 2
    for (int k0 = 0; k0 < DIM; k0 += 4) {
        float4 w0 = Wv[(k0 + 0) * 32 + cg];
        float4 w1 = Wv[(k0 + 1) * 32 + cg];
        float4 w2 = Wv[(k0 + 2) * 32 + cg];
        float4 w3 = Wv[(k0 + 3) * 32 + cg];
        #pragma unroll
        for (int i = 0; i < 8; ++i) {
            float4 a4 = *(const float4*)&us[8 * rg + i][k0];
            acc[i][0] = fmaf(a4.x, w0.x, fmaf(a4.y, w1.x, fmaf(a4.z, w2.x, fmaf(a4.w, w3.x, acc[i][0]))));
            acc[i][1] = fmaf(a4.x, w0.y, fmaf(a4.y, w1.y, fmaf(a4.z, w2.y, fmaf(a4.w, w3.y, acc[i][1]))));
            acc[i][2] = fmaf(a4.x, w0.z, fmaf(a4.y, w1.z, fmaf(a4.z, w2.z, fmaf(a4.w, w3.z, acc[i][2]))));
            acc[i][3] = fmaf(a4.x, w0.w, fmaf(a4.y, w1.w, fmaf(a4.z, w2.w, fmaf(a4.w, w3.w, acc[i][3]))));
        }
    }
    float4 bv = *(const float4*)(gb + (size_t)g * DIM + 4 * cg);
    size_t UD = (size_t)U * DIM;
    T* cOut = cbase + (size_t)g * UD;
    T* aOut = abase + (size_t)g * UD;
    #pragma unroll
    for (int i = 0; i < 8; ++i) {
        int lr = 8 * rg + i;
        int r = row0 + lr;
        if (r < U) {
            float4 uval = *(const float4*)&us[lr][4 * cg];
            float4 o;
            o.x = uval.x / (1.f + __expf(-(acc[i][0] + bv.x)));
            o.y = uval.y / (1.f + __expf(-(acc[i][1] + bv.y)));
            o.z = uval.z / (1.f + __expf(-(acc[i][2] + bv.z)));
            o.w = uval.w / (1.f + __expf(-(acc[i][3] + bv.w)));
            size_t oo = (size_t)r * DIM + 4 * cg;
            VecIO<T>::st4(cOut + oo, o);
            VecIO<T>::st4(aOut + oo, o);
        }
    }
}

// ---------------- orchestration ----------------
template <typename T>
static void run_all(const float* user_emb, const float* item_emb,
                    const float* gating_w, const float* gating_b,
                    const float* attn, const float* attn_mat,
                    const int* hs_row, const int* hs_col, const float* hs_val, int E_hs,
                    const int* hj_row, const int* hj_col, const float* hj_val, int E_hj,
                    const int* hp_row, const int* hp_col, const float* hp_val, int E_hp,
                    const int* r_row, const int* r_col, const float* r_val, int E_r,
                    int U, int I, float* out_user, float* out_item,
                    char* ws, hipStream_t stream) {
    const size_t UD = (size_t)U * DIM, ID = (size_t)I * DIM;
    char* p = ws;
    auto alloc = [&](size_t bytes) -> void* {
        void* r = (void*)p;
        p += (bytes + 255) & ~(size_t)255;
        return r;
    };
    T* S[5];
    for (int i = 0; i < 5; ++i) S[i] = (T*)alloc(UD * sizeof(T));  // contiguous: gate writes S[0..3]
    T* A = (T*)alloc(4 * UD * sizeof(T));                          // A1,A2,A3,AS contiguous
    T* itemA = (T*)alloc(ID * sizeof(T));
    T* itemB = (T*)alloc(ID * sizeof(T));
    float* wv  = (float*)alloc(DIM * sizeof(float));
    // contiguous offset + cursor regions: [hs|hj|hp|ru : U+1 each][ri : I+1]
    size_t offT = 4 * (size_t)(U + 1) + (size_t)(I + 1);
    int* off_all    = (int*)alloc(offT * 4);
    int* cursor_all = (int*)alloc(offT * 4);
    int* bsums_all  = (int*)alloc(5 * 1024 * 4);
    int*   scol_hs = (int*)alloc((size_t)E_hs * 4);
    float* sval_hs = (float*)alloc((size_t)E_hs * 4);
    int*   scol_hj = (int*)alloc((size_t)E_hj * 4);
    float* sval_hj = (float*)alloc((size_t)E_hj * 4);
    int*   scol_hp = (int*)alloc((size_t)E_hp * 4);
    float* sval_hp = (float*)alloc((size_t)E_hp * 4);
    int*   scol_ru = (int*)alloc((size_t)E_r * 4);
    float* sval_ru = (float*)alloc((size_t)E_r * 4);
    int*   scol_ri = (int*)alloc((size_t)E_r * 4);
    float* sval_ri = (float*)alloc((size_t)E_r * 4);

    int* off_hs = off_all;
    int* off_hj = off_all + (U + 1);
    int* off_hp = off_all + 2 * (size_t)(U + 1);
    int* off_ru = off_all + 3 * (size_t)(U + 1);
    int* off_ri = off_all + 4 * (size_t)(U + 1);

    // ---- fused CSR build for all 5 operators ----
    {
        P5ci rows{{hs_row, hj_row, hp_row, r_row, r_col}};
        P5ci cols{{hs_col, hj_col, hp_col, r_col, r_row}};
        P5cf vals{{hs_val, hj_val, hp_val, r_val, r_val}};
        I5 Es{{E_hs, E_hj, E_hp, E_r, E_r}};
        P5i counts{{off_hs, off_hj, off_hp, off_ru, off_ri}};
        P5i curs{{cursor_all, cursor_all + (U + 1), cursor_all + 2 * (size_t)(U + 1),
                  cursor_all + 3 * (size_t)(U + 1), cursor_all + 4 * (size_t)(U + 1)}};
        P5i scols{{scol_hs, scol_hj, scol_hp, scol_ru, scol_ri}};
        P5f svals{{sval_hs, sval_hj, sval_hp, sval_ru, sval_ri}};
        I5 ns{{U + 1, U + 1, U + 1, U + 1, I + 1}};
        int nbU = (U + 1 + 1023) / 1024, nbI = (I + 1 + 1023) / 1024;
        I5 nbs{{nbU, nbU, nbU, nbU, nbI}};
        int nbMax = nbU > nbI ? nbU : nbI;
        P5i bs{{bsums_all, bsums_all + 1024, bsums_all + 2048, bsums_all + 3072, bsums_all + 4096}};
        P5ci bsc{{bsums_all, bsums_all + 1024, bsums_all + 2048, bsums_all + 3072, bsums_all + 4096}};
        int maxE = E_hs;
        if (E_hj > maxE) maxE = E_hj;
        if (E_hp > maxE) maxE = E_hp;
        if (E_r  > maxE) maxE = E_r;
        int ge = (maxE + 255) / 256;
        P5i nulls{{nullptr, nullptr, nullptr, nullptr, nullptr}};

        hipMemsetAsync(off_all, 0, offT * 4, stream);
        k_hist_all<<<dim3(ge, 5), 256, 0, stream>>>(rows, Es, counts);
        k_scan_tile_m<<<dim3(nbMax, 5), 256, 0, stream>>>(counts, ns, bs, 1);
        k_scan_tile_m<<<dim3(1, 5), 256, 0, stream>>>(bs, nbs, nulls, 0);
        k_scan_add_m<<<dim3(nbMax, 5), 256, 0, stream>>>(counts, ns, bsc);
        hipMemcpyAsync(cursor_all, off_all, offT * 4, hipMemcpyDeviceToDevice, stream);
        k_scatter_all<<<dim3(ge, 5), 256, 0, stream>>>(rows, cols, vals, Es, curs, scols, svals);
    }

    k_attn_w<<<1, 128, 0, stream>>>(attn_mat, attn, wv);
    dim3 gg((U + 63) / 64, 4);
    k_gate<T><<<gg, 256, 0, stream>>>(user_emb, gating_w, gating_b, S[0], A, U);
    k_cvt<T><<<(int)((ID / 2 + 255) / 256), 256, 0, stream>>>(item_emb, itemA, (int)(ID / 2));
    hipMemcpyAsync(out_item, item_emb, ID * sizeof(float), hipMemcpyDeviceToDevice, stream);

    T *A1 = A, *A2 = A + UD, *A3 = A + 2 * UD, *AS = A + 3 * UD;
    T *c1 = S[0], *c2 = S[1], *c3 = S[2], *sp = S[3], *spare = S[4];
    T *itc = itemA, *itn = itemB;
    float* mixed = out_user;  // f32 scratch aliasing output region (fully rewritten later)
    int gbU = (U + 3) / 4, gbI = (I + 3) / 4;

    for (int layer = 0; layer < 2; ++layer) {
        k_attn_mix<T><<<gbU, 256, 0, stream>>>(c1, c2, c3, sp, wv, mixed, U);
        k_spmm<T, T, T><<<gbU, 256, 0, stream>>>(off_hs, scol_hs, sval_hs, c1, spare, A1, U);
        k_spmm<T, T, T><<<gbU, 256, 0, stream>>>(off_hj, scol_hj, sval_hj, c2, c1, A2, U);
        k_spmm<T, T, T><<<gbU, 256, 0, stream>>>(off_hp, scol_hp, sval_hp, c3, c2, A3, U);
        k_spmm<float, T, float><<<gbI, 256, 0, stream>>>(off_ri, scol_ri, sval_ri, mixed, itn, out_item, I);
        k_spmm<T, T, T><<<gbU, 256, 0, stream>>>(off_ru, scol_ru, sval_ru, itc, c3, AS, U);
        // rotate: (c1,c2,c3,sp,spare) <- (spare, c1, c2, c3, sp)  [buffers, not values]
        T* t0 = spare; T* t1 = c1; T* t2 = c2; T* t3 = c3; T* t4 = sp;
        c1 = t0; c2 = t1; c3 = t2; sp = t3; spare = t4;
        T* tt = itc; itc = itn; itn = tt;
    }
    k_attn_mix<T><<<gbU, 256, 0, stream>>>(A1, A2, A3, AS, wv, out_user, U);
}

extern "C" void kernel_launch(void* const* d_in, const int* in_sizes, int n_in,
                              void* d_out, int out_size, void* d_ws, size_t ws_size,
                              hipStream_t stream) {
    const float* user_emb = (const float*)d_in[0];
    const float* item_emb = (const float*)d_in[1];
    const float* gating_w = (const float*)d_in[2];
    const float* gating_b = (const float*)d_in[3];
    const float* attn     = (const float*)d_in[4];
    const float* attn_mat = (const float*)d_in[5];
    const int*   hs_row = (const int*)d_in[6];
    const int*   hs_col = (const int*)d_in[7];
    const float* hs_val = (const float*)d_in[8];
    const int*   hj_row = (const int*)d_in[9];
    const int*   hj_col = (const int*)d_in[10];
    const float* hj_val = (const float*)d_in[11];
    const int*   hp_row = (const int*)d_in[12];
    const int*   hp_col = (const int*)d_in[13];
    const float* hp_val = (const float*)d_in[14];
    const int*   r_row  = (const int*)d_in[15];
    const int*   r_col  = (const int*)d_in[16];
    const float* r_val  = (const float*)d_in[17];

    const int U = in_sizes[0] / DIM;
    const int I = in_sizes[1] / DIM;
    const int E_hs = in_sizes[6], E_hj = in_sizes[9], E_hp = in_sizes[12], E_r = in_sizes[15];
    const size_t UD = (size_t)U * DIM, ID = (size_t)I * DIM;

    float* out_user = (float*)d_out;
    float* out_item = out_user + UD;

    // footprint (256B-aligned per alloc; generous slack)
    size_t csr = 2 * ((size_t)E_hs + E_hj + E_hp + 2 * (size_t)E_r) * 4;
    size_t offs = 2 * (4 * (size_t)(U + 1) + (I + 1)) * 4 + 4 * 5 * 1024 + DIM * 4 + (1 << 16);
    size_t reqF = 9 * UD * 4 + 2 * ID * 4 + csr + offs;

    if (ws_size >= reqF) {
        run_all<float>(user_emb, item_emb, gating_w, gating_b, attn, attn_mat,
                       hs_row, hs_col, hs_val, E_hs, hj_row, hj_col, hj_val, E_hj,
                       hp_row, hp_col, hp_val, E_hp, r_row, r_col, r_val, E_r,
                       U, I, out_user, out_item, (char*)d_ws, stream);
    } else {
        run_all<bf16t>(user_emb, item_emb, gating_w, gating_b, attn, attn_mat,
                       hs_row, hs_col, hs_val, E_hs, hj_row, hj_col, hj_val, E_hj,
                       hp_row, hp_col, hp_val, E_hp, r_row, r_col, r_val, E_r,
                       U, I, out_user, out_item, (char*)d_ws, stream);
    }
}

// Round 8
// 1654.314 us; speedup vs baseline: 1.6507x; 1.0326x over previous
//
#include <hip/hip_runtime.h>
#include <cstdint>

#define DIM 128

typedef unsigned short bf16t;

__device__ __forceinline__ unsigned short f2bf_bits(float f) {
    union { float f; uint32_t u; } x; x.f = f;
    uint32_t r = x.u + 0x7FFFu + ((x.u >> 16) & 1u);  // RN-even
    return (unsigned short)(r >> 16);
}

template <typename T> struct VecIO;
template <> struct VecIO<float> {
    static __device__ __forceinline__ float2 ld2(const float* p, size_t i) {
        return ((const float2*)p)[i];
    }
    static __device__ __forceinline__ void st2(float* p, size_t i, float2 v) {
        ((float2*)p)[i] = v;
    }
    static __device__ __forceinline__ void st4(float* p, float4 v) {
        *(float4*)p = v;
    }
};
template <> struct VecIO<bf16t> {
    static __device__ __forceinline__ float2 ld2(const bf16t* p, size_t i) {
        uint32_t u = ((const uint32_t*)p)[i];
        union { uint32_t u; float f; } a, b;
        a.u = u << 16; b.u = u & 0xFFFF0000u;
        return make_float2(a.f, b.f);
    }
    static __device__ __forceinline__ void st2(bf16t* p, size_t i, float2 v) {
        uint32_t lo = f2bf_bits(v.x), hi = f2bf_bits(v.y);
        ((uint32_t*)p)[i] = lo | (hi << 16);
    }
    static __device__ __forceinline__ void st4(bf16t* p, float4 v) {
        uint32_t lo = (uint32_t)f2bf_bits(v.x) | ((uint32_t)f2bf_bits(v.y) << 16);
        uint32_t hi = (uint32_t)f2bf_bits(v.z) | ((uint32_t)f2bf_bits(v.w) << 16);
        *(uint2*)p = make_uint2(lo, hi);
    }
};

__device__ __forceinline__ float wave_reduce_sum(float v) {
    #pragma unroll
    for (int m = 32; m > 0; m >>= 1) v += __shfl_xor(v, m, 64);
    return v;
}

// ---------------- fused CSR build (5 matrices via blockIdx.y) ----------------
struct P5ci { const int* p[5]; };
struct P5cf { const float* p[5]; };
struct P5i  { int* p[5]; };
struct P5u2 { uint2* p[5]; };
struct I5   { int v[5]; };

__global__ __launch_bounds__(256) void k_hist_all(P5ci rows, I5 E, P5i counts) {
    int y = blockIdx.y;
    int e = blockIdx.x * 256 + threadIdx.x;
    if (e < E.v[y]) atomicAdd(&counts.p[y][rows.p[y][e] + 1], 1);
}

// in-place inclusive scan of d[y][0..n) in 1024-elem tiles; bsums[y][b] = tile total
__global__ __launch_bounds__(256) void k_scan_tile_m(P5i dd, I5 nn, P5i bsums, int has_bsums) {
    __shared__ int sh[256];
    int y = blockIdx.y;
    int* d = dd.p[y];
    int n = nn.v[y];
    int t = threadIdx.x;
    int base = blockIdx.x * 1024 + t * 4;
    int v0 = (base + 0 < n) ? d[base + 0] : 0;
    int v1 = (base + 1 < n) ? d[base + 1] : 0;
    int v2 = (base + 2 < n) ? d[base + 2] : 0;
    int v3 = (base + 3 < n) ? d[base + 3] : 0;
    v1 += v0; v2 += v1; v3 += v2;
    sh[t] = v3;
    __syncthreads();
    #pragma unroll
    for (int off = 1; off < 256; off <<= 1) {
        int x = (t >= off) ? sh[t - off] : 0;
        __syncthreads();
        if (t >= off) sh[t] += x;
        __syncthreads();
    }
    int excl = (t > 0) ? sh[t - 1] : 0;
    v0 += excl; v1 += excl; v2 += excl; v3 += excl;
    if (base + 0 < n) d[base + 0] = v0;
    if (base + 1 < n) d[base + 1] = v1;
    if (base + 2 < n) d[base + 2] = v2;
    if (base + 3 < n) d[base + 3] = v3;
    if (t == 255 && has_bsums) bsums.p[y][blockIdx.x] = sh[255];
}

__global__ __launch_bounds__(256) void k_scan_add_m(P5i dd, I5 nn, P5ci bsums) {
    if (blockIdx.x == 0) return;
    int y = blockIdx.y;
    int* d = dd.p[y];
    int n = nn.v[y];
    int add = bsums.p[y][blockIdx.x - 1];
    int base = blockIdx.x * 1024 + threadIdx.x * 4;
    #pragma unroll
    for (int i = 0; i < 4; ++i)
        if (base + i < n) d[base + i] += add;
}

// writes fused (col,val) 8B pairs -> one dirty cache line per edge, not two
__global__ __launch_bounds__(256) void k_scatter_all(P5ci rows, P5ci cols, P5cf vals,
                                                     I5 E, P5i cursor, P5u2 spair) {
    int y = blockIdx.y;
    int e = blockIdx.x * 256 + threadIdx.x;
    if (e < E.v[y]) {
        int r = rows.p[y][e];
        int p = atomicAdd(&cursor.p[y][r], 1);
        spair.p[y][p] = make_uint2((uint32_t)cols.p[y][e], __float_as_uint(vals.p[y][e]));
    }
}

// ---------------- small prep ----------------
// w[k] = sum_d attn_mat[k][d] * attn[d]
__global__ __launch_bounds__(128) void k_attn_w(const float* __restrict__ attn_mat,
                                                const float* __restrict__ attn,
                                                float* __restrict__ w) {
    int k = threadIdx.x;
    float s = 0.f;
    for (int d = 0; d < DIM; ++d) s += attn_mat[k * DIM + d] * attn[d];
    w[k] = s;
}

template <typename T>
__global__ __launch_bounds__(256) void k_cvt(const float* __restrict__ src,
                                             T* __restrict__ dst, int n2) {
    int i = blockIdx.x * 256 + threadIdx.x;
    if (i < n2) VecIO<T>::st2(dst, i, ((const float2*)src)[i]);
}

// ---------------- channel attention + mix (+0.5*add) ----------------
template <typename TI>
__global__ __launch_bounds__(256) void k_attn_mix(const TI* __restrict__ e1,
                                                  const TI* __restrict__ e2,
                                                  const TI* __restrict__ e3,
                                                  const TI* __restrict__ add,
                                                  const float* __restrict__ w,
                                                  float* __restrict__ out, int n) {
    int wid = threadIdx.x >> 6, lane = threadIdx.x & 63;
    int u = blockIdx.x * 4 + wid;
    if (u >= n) return;
    size_t idx = (size_t)u * 64 + lane;
    float2 a = VecIO<TI>::ld2(e1, idx);
    float2 b = VecIO<TI>::ld2(e2, idx);
    float2 c = VecIO<TI>::ld2(e3, idx);
    float2 s = VecIO<TI>::ld2(add, idx);
    float2 wv = ((const float2*)w)[lane];
    float t1 = a.x * wv.x + a.y * wv.y;
    float t2 = b.x * wv.x + b.y * wv.y;
    float t3 = c.x * wv.x + c.y * wv.y;
    #pragma unroll
    for (int m = 32; m > 0; m >>= 1) {
        t1 += __shfl_xor(t1, m, 64);
        t2 += __shfl_xor(t2, m, 64);
        t3 += __shfl_xor(t3, m, 64);
    }
    float mx = fmaxf(t1, fmaxf(t2, t3));
    float x1 = __expf(t1 - mx), x2 = __expf(t2 - mx), x3 = __expf(t3 - mx);
    float inv = 1.f / (x1 + x2 + x3);
    x1 *= inv; x2 *= inv; x3 *= inv;
    float2 o;
    o.x = x1 * a.x + x2 * b.x + x3 * c.x + 0.5f * s.x;
    o.y = x1 * a.y + x2 * b.y + x3 * c.y + 0.5f * s.y;
    ((float2*)out)[idx] = o;
}

// ---------------- CSR spmm + fused l2-normalize accumulate ----------------
// y[r] = sum_j val_j * x[col_j];  acc[r] += y[r] / max(||y[r]||, 1e-12)
// 4x edge unroll -> 4 row-gathers in flight per wave; (col,val) as one 8B pair.
template <typename TI, typename TO, typename TA>
__global__ __launch_bounds__(256) void k_spmm(const int* __restrict__ off,
                                              const uint2* __restrict__ spair,
                                              const TI* __restrict__ x,
                                              TO* __restrict__ y,
                                              TA* __restrict__ acc, int n) {
    int wid = threadIdx.x >> 6, lane = threadIdx.x & 63;
    int r = blockIdx.x * 4 + wid;
    if (r >= n) return;
    int b = off[r], e = off[r + 1];
    float2 s = make_float2(0.f, 0.f);
    int j = b;
    for (; j + 4 <= e; j += 4) {
        uint2 p0 = spair[j + 0], p1 = spair[j + 1], p2 = spair[j + 2], p3 = spair[j + 3];
        float2 x0 = VecIO<TI>::ld2(x, (size_t)p0.x * 64 + lane);
        float2 x1 = VecIO<TI>::ld2(x, (size_t)p1.x * 64 + lane);
        float2 x2 = VecIO<TI>::ld2(x, (size_t)p2.x * 64 + lane);
        float2 x3 = VecIO<TI>::ld2(x, (size_t)p3.x * 64 + lane);
        float v0 = __uint_as_float(p0.y), v1 = __uint_as_float(p1.y);
        float v2 = __uint_as_float(p2.y), v3 = __uint_as_float(p3.y);
        s.x = fmaf(v0, x0.x, s.x); s.y = fmaf(v0, x0.y, s.y);
        s.x = fmaf(v1, x1.x, s.x); s.y = fmaf(v1, x1.y, s.y);
        s.x = fmaf(v2, x2.x, s.x); s.y = fmaf(v2, x2.y, s.y);
        s.x = fmaf(v3, x3.x, s.x); s.y = fmaf(v3, x3.y, s.y);
    }
    for (; j < e; ++j) {
        uint2 pr = spair[j];
        float v = __uint_as_float(pr.y);
        float2 xv = VecIO<TI>::ld2(x, (size_t)pr.x * 64 + lane);
        s.x = fmaf(v, xv.x, s.x);
        s.y = fmaf(v, xv.y, s.y);
    }
    size_t idx = (size_t)r * 64 + lane;
    VecIO<TO>::st2(y, idx, s);
    float q = wave_reduce_sum(s.x * s.x + s.y * s.y);
    float rn = 1.f / fmaxf(sqrtf(q), 1e-12f);
    float2 av = VecIO<TA>::ld2(acc, idx);
    av.x = fmaf(s.x, rn, av.x);
    av.y = fmaf(s.y, rn, av.y);
    VecIO<TA>::st2(acc, idx, av);
}

// ---------------- gated GEMM: out = ue * sigmoid(ue @ W_g + b_g) ----------------
// W is used in its NATIVE [k][c] layout: lane cg reads W[k][4cg..4cg+3] -> fully
// coalesced 512B wave reads (L1/L2-resident, 64KB/gate). 64 rows/block in LDS,
// 8x4 register blocking; A-reads are same-address LDS broadcasts (conflict-free).
template <typename T>
__global__ __launch_bounds__(256, 4) void k_gate(const float* __restrict__ ue,
                                                 const float* __restrict__ gw,
                                                 const float* __restrict__ gb,
                                                 T* __restrict__ cbase,
                                                 T* __restrict__ abase, int U) {
    __shared__ float us[64][DIM];
    int g = blockIdx.y;
    const float4* Wv = (const float4*)(gw + (size_t)g * DIM * DIM);  // [k][c4]
    int tid = threadIdx.x;
    int cg = tid & 31, rg = tid >> 5;  // cols 4cg..4cg+3; local rows 8rg..8rg+7
    int row0 = blockIdx.x * 64;
    int nr = U - row0; if (nr > 64) nr = 64;
    {
        const float4* src = (const float4*)(ue + (size_t)row0 * DIM);
        float4* dst = (float4*)us;
        int tot = nr * 32;
        for (int i = tid; i < tot; i += 256) dst[i] = src[i];
    }
    __syncthreads();
    float acc[8][4];
    #pragma unroll
    for (int i = 0; i < 8; ++i) {
        acc[i][0] = 0.f; acc[i][1] = 0.f; acc[i][2] = 0.f; acc[i][3] = 0.f;
    }
    #pragma unroll 2
    for (int k0 = 0; k0 < DIM; k0 += 4) {
        float4 w0 = Wv[(k0 + 0) * 32 + cg];
        float4 w1 = Wv[(k0 + 1) * 32 + cg];
        float4 w2 = Wv[(k0 + 2) * 32 + cg];
        float4 w3 = Wv[(k0 + 3) * 32 + cg];
        #pragma unroll
        for (int i = 0; i < 8; ++i) {
            float4 a4 = *(const float4*)&us[8 * rg + i][k0];
            acc[i][0] = fmaf(a4.x, w0.x, fmaf(a4.y, w1.x, fmaf(a4.z, w2.x, fmaf(a4.w, w3.x, acc[i][0]))));
            acc[i][1] = fmaf(a4.x, w0.y, fmaf(a4.y, w1.y, fmaf(a4.z, w2.y, fmaf(a4.w, w3.y, acc[i][1]))));
            acc[i][2] = fmaf(a4.x, w0.z, fmaf(a4.y, w1.z, fmaf(a4.z, w2.z, fmaf(a4.w, w3.z, acc[i][2]))));
            acc[i][3] = fmaf(a4.x, w0.w, fmaf(a4.y, w1.w, fmaf(a4.z, w2.w, fmaf(a4.w, w3.w, acc[i][3]))));
        }
    }
    float4 bv = *(const float4*)(gb + (size_t)g * DIM + 4 * cg);
    size_t UD = (size_t)U * DIM;
    T* cOut = cbase + (size_t)g * UD;
    T* aOut = abase + (size_t)g * UD;
    #pragma unroll
    for (int i = 0; i < 8; ++i) {
        int lr = 8 * rg + i;
        int r = row0 + lr;
        if (r < U) {
            float4 uval = *(const float4*)&us[lr][4 * cg];
            float4 o;
            o.x = uval.x / (1.f + __expf(-(acc[i][0] + bv.x)));
            o.y = uval.y / (1.f + __expf(-(acc[i][1] + bv.y)));
            o.z = uval.z / (1.f + __expf(-(acc[i][2] + bv.z)));
            o.w = uval.w / (1.f + __expf(-(acc[i][3] + bv.w)));
            size_t oo = (size_t)r * DIM + 4 * cg;
            VecIO<T>::st4(cOut + oo, o);
            VecIO<T>::st4(aOut + oo, o);
        }
    }
}

// ---------------- orchestration ----------------
template <typename T>
static void run_all(const float* user_emb, const float* item_emb,
                    const float* gating_w, const float* gating_b,
                    const float* attn, const float* attn_mat,
                    const int* hs_row, const int* hs_col, const float* hs_val, int E_hs,
                    const int* hj_row, const int* hj_col, const float* hj_val, int E_hj,
                    const int* hp_row, const int* hp_col, const float* hp_val, int E_hp,
                    const int* r_row, const int* r_col, const float* r_val, int E_r,
                    int U, int I, float* out_user, float* out_item,
                    char* ws, hipStream_t stream) {
    const size_t UD = (size_t)U * DIM, ID = (size_t)I * DIM;
    char* p = ws;
    auto alloc = [&](size_t bytes) -> void* {
        void* r = (void*)p;
        p += (bytes + 255) & ~(size_t)255;
        return r;
    };
    T* S[5];
    for (int i = 0; i < 5; ++i) S[i] = (T*)alloc(UD * sizeof(T));  // contiguous: gate writes S[0..3]
    T* A = (T*)alloc(4 * UD * sizeof(T));                          // A1,A2,A3,AS contiguous
    T* itemA = (T*)alloc(ID * sizeof(T));
    T* itemB = (T*)alloc(ID * sizeof(T));
    float* wv  = (float*)alloc(DIM * sizeof(float));
    // contiguous offset + cursor regions: [hs|hj|hp|ru : U+1 each][ri : I+1]
    size_t offT = 4 * (size_t)(U + 1) + (size_t)(I + 1);
    int* off_all    = (int*)alloc(offT * 4);
    int* cursor_all = (int*)alloc(offT * 4);
    int* bsums_all  = (int*)alloc(5 * 1024 * 4);
    uint2* pair_hs = (uint2*)alloc((size_t)E_hs * 8);
    uint2* pair_hj = (uint2*)alloc((size_t)E_hj * 8);
    uint2* pair_hp = (uint2*)alloc((size_t)E_hp * 8);
    uint2* pair_ru = (uint2*)alloc((size_t)E_r * 8);
    uint2* pair_ri = (uint2*)alloc((size_t)E_r * 8);

    int* off_hs = off_all;
    int* off_hj = off_all + (U + 1);
    int* off_hp = off_all + 2 * (size_t)(U + 1);
    int* off_ru = off_all + 3 * (size_t)(U + 1);
    int* off_ri = off_all + 4 * (size_t)(U + 1);

    // ---- fused CSR build for all 5 operators ----
    {
        P5ci rows{{hs_row, hj_row, hp_row, r_row, r_col}};
        P5ci cols{{hs_col, hj_col, hp_col, r_col, r_row}};
        P5cf vals{{hs_val, hj_val, hp_val, r_val, r_val}};
        I5 Es{{E_hs, E_hj, E_hp, E_r, E_r}};
        P5i counts{{off_hs, off_hj, off_hp, off_ru, off_ri}};
        P5i curs{{cursor_all, cursor_all + (U + 1), cursor_all + 2 * (size_t)(U + 1),
                  cursor_all + 3 * (size_t)(U + 1), cursor_all + 4 * (size_t)(U + 1)}};
        P5u2 pairs{{pair_hs, pair_hj, pair_hp, pair_ru, pair_ri}};
        I5 ns{{U + 1, U + 1, U + 1, U + 1, I + 1}};
        int nbU = (U + 1 + 1023) / 1024, nbI = (I + 1 + 1023) / 1024;
        I5 nbs{{nbU, nbU, nbU, nbU, nbI}};
        int nbMax = nbU > nbI ? nbU : nbI;
        P5i bs{{bsums_all, bsums_all + 1024, bsums_all + 2048, bsums_all + 3072, bsums_all + 4096}};
        P5ci bsc{{bsums_all, bsums_all + 1024, bsums_all + 2048, bsums_all + 3072, bsums_all + 4096}};
        int maxE = E_hs;
        if (E_hj > maxE) maxE = E_hj;
        if (E_hp > maxE) maxE = E_hp;
        if (E_r  > maxE) maxE = E_r;
        int ge = (maxE + 255) / 256;
        P5i nulls{{nullptr, nullptr, nullptr, nullptr, nullptr}};

        hipMemsetAsync(off_all, 0, offT * 4, stream);
        k_hist_all<<<dim3(ge, 5), 256, 0, stream>>>(rows, Es, counts);
        k_scan_tile_m<<<dim3(nbMax, 5), 256, 0, stream>>>(counts, ns, bs, 1);
        k_scan_tile_m<<<dim3(1, 5), 256, 0, stream>>>(bs, nbs, nulls, 0);
        k_scan_add_m<<<dim3(nbMax, 5), 256, 0, stream>>>(counts, ns, bsc);
        hipMemcpyAsync(cursor_all, off_all, offT * 4, hipMemcpyDeviceToDevice, stream);
        k_scatter_all<<<dim3(ge, 5), 256, 0, stream>>>(rows, cols, vals, Es, curs, pairs);
    }

    k_attn_w<<<1, 128, 0, stream>>>(attn_mat, attn, wv);
    dim3 gg((U + 63) / 64, 4);
    k_gate<T><<<gg, 256, 0, stream>>>(user_emb, gating_w, gating_b, S[0], A, U);
    k_cvt<T><<<(int)((ID / 2 + 255) / 256), 256, 0, stream>>>(item_emb, itemA, (int)(ID / 2));
    hipMemcpyAsync(out_item, item_emb, ID * sizeof(float), hipMemcpyDeviceToDevice, stream);

    T *A1 = A, *A2 = A + UD, *A3 = A + 2 * UD, *AS = A + 3 * UD;
    T *c1 = S[0], *c2 = S[1], *c3 = S[2], *sp = S[3], *spare = S[4];
    T *itc = itemA, *itn = itemB;
    float* mixed = out_user;  // f32 scratch aliasing output region (fully rewritten later)
    int gbU = (U + 3) / 4, gbI = (I + 3) / 4;

    for (int layer = 0; layer < 2; ++layer) {
        k_attn_mix<T><<<gbU, 256, 0, stream>>>(c1, c2, c3, sp, wv, mixed, U);
        k_spmm<T, T, T><<<gbU, 256, 0, stream>>>(off_hs, pair_hs, c1, spare, A1, U);
        k_spmm<T, T, T><<<gbU, 256, 0, stream>>>(off_hj, pair_hj, c2, c1, A2, U);
        k_spmm<T, T, T><<<gbU, 256, 0, stream>>>(off_hp, pair_hp, c3, c2, A3, U);
        k_spmm<float, T, float><<<gbI, 256, 0, stream>>>(off_ri, pair_ri, mixed, itn, out_item, I);
        k_spmm<T, T, T><<<gbU, 256, 0, stream>>>(off_ru, pair_ru, itc, c3, AS, U);
        // rotate: (c1,c2,c3,sp,spare) <- (spare, c1, c2, c3, sp)  [buffers, not values]
        T* t0 = spare; T* t1 = c1; T* t2 = c2; T* t3 = c3; T* t4 = sp;
        c1 = t0; c2 = t1; c3 = t2; sp = t3; spare = t4;
        T* tt = itc; itc = itn; itn = tt;
    }
    k_attn_mix<T><<<gbU, 256, 0, stream>>>(A1, A2, A3, AS, wv, out_user, U);
}

extern "C" void kernel_launch(void* const* d_in, const int* in_sizes, int n_in,
                              void* d_out, int out_size, void* d_ws, size_t ws_size,
                              hipStream_t stream) {
    const float* user_emb = (const float*)d_in[0];
    const float* item_emb = (const float*)d_in[1];
    const float* gating_w = (const float*)d_in[2];
    const float* gating_b = (const float*)d_in[3];
    const float* attn     = (const float*)d_in[4];
    const float* attn_mat = (const float*)d_in[5];
    const int*   hs_row = (const int*)d_in[6];
    const int*   hs_col = (const int*)d_in[7];
    const float* hs_val = (const float*)d_in[8];
    const int*   hj_row = (const int*)d_in[9];
    const int*   hj_col = (const int*)d_in[10];
    const float* hj_val = (const float*)d_in[11];
    const int*   hp_row = (const int*)d_in[12];
    const int*   hp_col = (const int*)d_in[13];
    const float* hp_val = (const float*)d_in[14];
    const int*   r_row  = (const int*)d_in[15];
    const int*   r_col  = (const int*)d_in[16];
    const float* r_val  = (const float*)d_in[17];

    const int U = in_sizes[0] / DIM;
    const int I = in_sizes[1] / DIM;
    const int E_hs = in_sizes[6], E_hj = in_sizes[9], E_hp = in_sizes[12], E_r = in_sizes[15];
    const size_t UD = (size_t)U * DIM, ID = (size_t)I * DIM;

    float* out_user = (float*)d_out;
    float* out_item = out_user + UD;

    // footprint (256B-aligned per alloc; generous slack)
    size_t csr = ((size_t)E_hs + E_hj + E_hp + 2 * (size_t)E_r) * 8;
    size_t offs = 2 * (4 * (size_t)(U + 1) + (I + 1)) * 4 + 4 * 5 * 1024 + DIM * 4 + (1 << 16);
    size_t reqF = 9 * UD * 4 + 2 * ID * 4 + csr + offs;

    if (ws_size >= reqF) {
        run_all<float>(user_emb, item_emb, gating_w, gating_b, attn, attn_mat,
                       hs_row, hs_col, hs_val, E_hs, hj_row, hj_col, hj_val, E_hj,
                       hp_row, hp_col, hp_val, E_hp, r_row, r_col, r_val, E_r,
                       U, I, out_user, out_item, (char*)d_ws, stream);
    } else {
        run_all<bf16t>(user_emb, item_emb, gating_w, gating_b, attn, attn_mat,
                       hs_row, hs_col, hs_val, E_hs, hj_row, hj_col, hj_val, E_hj,
                       hp_row, hp_col, hp_val, E_hp, r_row, r_col, r_val, E_r,
                       U, I, out_user, out_item, (char*)d_ws, stream);
    }
}